// Round 1
// baseline (457.517 us; speedup 1.0000x reference)
//
#include <hip/hip_runtime.h>

// ReaxFF bond energy + segment_sum. N_BONDS=16777216, N_ATOMS=1048576, N_TYPES=16.
//
// R1-R3: global fp atomics are memory-side, 32B granule (~21 G/s wall).
// R4: exact radix partition, but 4B scattered stores write-amplified (373 MB).
// R5: LDS counting sort + sector-aligned run writes -> 181 us partition.
// R6: CB=8192, 39.5 KB LDS. Measured: occupancy 36% == 3 blocks/CU resident
//     (40448 B * 4 > 160 KB after rounding) -> latency-bound partition, 125 us.
// R7 (this): attack occupancy. Template CB; prefer CB=4096 -> LDS 20.8 KB ->
//     7 blocks/CU. Precompute bucket base prefix once (base_kernel) instead of
//     per-block scan2 + per-accum-block O(b) reduce. u16 counts (shrinks ws
//     need so the 4096/NR=2 tier fits more ws sizes). shfl scan (no scanb LDS).
//     Fallback tier CB=8192 now 37200 B -> 4 blocks/CU (was 3).

typedef float f32x4 __attribute__((ext_vector_type(4)));
typedef int   i32x4 __attribute__((ext_vector_type(4)));
typedef unsigned u32;
typedef unsigned short u16;

#define NB     512      // buckets; bucket covers 2048 atoms
#define RANGE  2048
#define SHIFT  11
#define TB     256
#define PADQ   8u       // run padding quantum (8 elems = 32 B = 1 HBM sector)

__device__ __forceinline__ u32 f32_to_bf16_bits(float f) {
    u32 u = __float_as_uint(f);
    return ((u + 0x7FFFu + ((u >> 16) & 1u)) >> 16) & 0xFFFFu;
}

// exclusive prefix over the 256-thread block of per-thread value v.
// shfl intra-wave scan + 4-word LDS wave-sum exchange. Contains a barrier.
__device__ __forceinline__ u32 block_excl_scan(u32 v, u32* wsum, int tid) {
    u32 s = v;
#pragma unroll
    for (int off = 1; off < 64; off <<= 1) {
        u32 n = __shfl_up(s, off);
        if ((tid & 63) >= off) s += n;
    }
    if ((tid & 63) == 63) wsum[tid >> 6] = s;
    __syncthreads();
    int w = tid >> 6;
    u32 wb = 0;
#pragma unroll
    for (int ww = 0; ww < 3; ++ww) wb += (ww < w) ? wsum[ww] : 0u;
    return wb + s - v;
}

// ---- Pass A: per-superblock bucket counts (per-wave LDS hist) ----
template<int CBK>
__global__ __launch_bounds__(TB) void count_kernel(
        const i32x4* __restrict__ atom_i, u16* __restrict__ counts,
        int round_start) {
    __shared__ u32 hist[4][NB];
    int tid = threadIdx.x, w = tid >> 6;
    for (int i = tid; i < 4 * NB; i += TB) ((u32*)hist)[i] = 0u;
    __syncthreads();
    long base4 = ((long)round_start + (long)blockIdx.x * CBK) >> 2;
#pragma unroll
    for (int it = 0; it < CBK / (TB * 4); ++it) {
        i32x4 a = __builtin_nontemporal_load(&atom_i[base4 + it * TB + tid]);
        atomicAdd(&hist[w][(u32)a.x >> SHIFT], 1u);
        atomicAdd(&hist[w][(u32)a.y >> SHIFT], 1u);
        atomicAdd(&hist[w][(u32)a.z >> SHIFT], 1u);
        atomicAdd(&hist[w][(u32)a.w >> SHIFT], 1u);
    }
    __syncthreads();
    for (int b = tid; b < NB; b += TB)
        counts[(size_t)blockIdx.x * NB + b] =
            (u16)(hist[0][b] + hist[1][b] + hist[2][b] + hist[3][b]);
}

// ---- S1: per-bucket exclusive scan of PADDED counts over superblocks ----
__global__ __launch_bounds__(TB) void scan_cols_kernel(
        const u16* __restrict__ counts, u32* __restrict__ offs,
        u32* __restrict__ total, int nsb) {
    __shared__ u32 sc[TB];
    int b = blockIdx.x, t = threadIdx.x;
    int vpt = nsb >> 8;                 // nsb multiple of 256, vpt <= 16
    u32 v[16];
    u32 s = 0;
    for (int k = 0; k < vpt; ++k) {
        u32 c = counts[(size_t)(t * vpt + k) * NB + b];
        c = (c + PADQ - 1u) & ~(PADQ - 1u);
        v[k] = s; s += c;
    }
    sc[t] = s;
    __syncthreads();
    for (int off = 1; off < TB; off <<= 1) {
        u32 u = (t >= off) ? sc[t - off] : 0u;
        __syncthreads();
        sc[t] += u;
        __syncthreads();
    }
    u32 excl = sc[t] - s;
    for (int k = 0; k < vpt; ++k)
        offs[(size_t)(t * vpt + k) * NB + b] = excl + v[k];
    if (t == TB - 1) total[b] = sc[t];
}

// ---- S2: bucket base = exclusive prefix of padded bucket totals (once) ----
__global__ __launch_bounds__(TB) void base_kernel(
        const u32* __restrict__ total, u32* __restrict__ gbase) {
    __shared__ u32 wsum[4];
    int t = threadIdx.x;
    u32 t0 = total[2 * t], t1 = total[2 * t + 1];
    u32 excl = block_excl_scan(t0 + t1, wsum, t);
    gbase[2 * t]     = excl;
    gbase[2 * t + 1] = excl + t0;
}

// ---- Pass B: compute e, LDS counting sort, coalesced padded run writes ----
template<int CBK, int MINB>
__global__ __launch_bounds__(TB, MINB) void partition_kernel(
        const i32x4* __restrict__ bt, const i32x4* __restrict__ ai,
        const f32x4* __restrict__ bs_, const f32x4* __restrict__ bp_,
        const f32x4* __restrict__ bpp_, const float* __restrict__ bond_params,
        const u16* __restrict__ counts, const u32* __restrict__ offs,
        const u32* __restrict__ gbase, u32* __restrict__ arena,
        int round_start) {
    __shared__ u32   sorted[CBK];       // 16 KB (4096) / 32 KB (8192)
    __shared__ u32   start_[NB], cur[NB];
    __shared__ u32   wsum[4];
    __shared__ float4 sp_a[16];         // de_s, de_p, de_pp, p_be1
    __shared__ float  sp_b[16];         // p_be2

    int tid = threadIdx.x, sb = blockIdx.x;
    if (tid < 16) {
        const float* p = bond_params + tid * 5;
        sp_a[tid] = make_float4(p[0], p[1], p[2], p[3]);
        sp_b[tid] = p[4];
    }
    // count row -> cursor starts (local layout); single shfl scan, no scanb
    u32 c01 = ((const u32*)(counts + (size_t)sb * NB))[tid];
    u32 c0 = c01 & 0xFFFFu, c1 = c01 >> 16;
    u32 excl = block_excl_scan(c0 + c1, wsum, tid);
    start_[2 * tid]     = excl;       cur[2 * tid]     = excl;
    start_[2 * tid + 1] = excl + c0;  cur[2 * tid + 1] = excl + c0;
    __syncthreads();

    long base4 = ((long)round_start + (long)sb * CBK) >> 2;
#pragma unroll
    for (int it = 0; it < CBK / (TB * 4); ++it) {
        long idx = base4 + it * TB + tid;
        i32x4 t  = __builtin_nontemporal_load(&bt[idx]);
        i32x4 a  = __builtin_nontemporal_load(&ai[idx]);
        f32x4 s  = __builtin_nontemporal_load(&bs_[idx]);
        f32x4 p  = __builtin_nontemporal_load(&bp_[idx]);
        f32x4 pp = __builtin_nontemporal_load(&bpp_[idx]);
#pragma unroll
        for (int k = 0; k < 4; ++k) {
            u32 ak = (u32)a[k];
            float4 pa = sp_a[t[k]];      // one ds_read_b128
            float  pb = sp_b[t[k]];      // one ds_read_b32
            float pw = __powf(s[k], pb); // s in (0.05,1) -> safe
            float e  = -pa.x * s[k] * __expf(pa.w * (1.0f - pw))
                       - pa.y * p[k] - pa.z * pp[k];
            u32 b = ak >> SHIFT;
            u32 pos = atomicAdd(&cur[b], 1u);
            sorted[pos] = ((ak & (RANGE - 1u)) << 16) | f32_to_bf16_bits(e);
        }
    }
    __syncthreads();

    // copy-out: LG lanes per bucket; run start 32 B-aligned (PADQ)
    constexpr int LG  = (CBK >= 8192) ? 16 : 8;
    constexpr int GPW = 64 / LG;        // bucket groups per wave
    int w = tid >> 6, lane = tid & 63;
    int gi = lane / LG, j0 = lane % LG;
    for (int b = w * GPW + gi; b < NB; b += 4 * GPW) {
        u32 end = cur[b], ls = start_[b], len = end - ls;
        u32 plen = (len + PADQ - 1u) & ~(PADQ - 1u);
        u32 g = gbase[b] + offs[(size_t)sb * NB + b];
        for (u32 j = j0; j < plen; j += LG)
            arena[g + j] = (j < len) ? sorted[ls + j] : 0u;
    }
}

// ---- Pass C: per-bucket LDS accumulation (per-wave replicas) ----
__global__ __launch_bounds__(TB, 4) void accum_kernel(
        const u32* __restrict__ arena, const u32* __restrict__ total,
        const u32* __restrict__ gbase, float* __restrict__ out, int add_prev) {
    __shared__ float acc[4][RANGE];     // 32 KB
    int tid = threadIdx.x, w = tid >> 6, b = blockIdx.x;
    for (int i = tid; i < RANGE; i += TB) {
        acc[0][i] = 0.f; acc[1][i] = 0.f; acc[2][i] = 0.f; acc[3][i] = 0.f;
    }
    __syncthreads();
    u32 s0 = gbase[b];                  // exclusive prefix of padded totals
    u32 n  = total[b];                  // multiple of 8
    const uint4* src = (const uint4*)(arena + s0);
    for (u32 j = tid; j < (n >> 2); j += TB) {
        uint4 e = src[j];
        if (e.x) atomicAdd(&acc[w][e.x >> 16], __uint_as_float((e.x & 0xFFFFu) << 16));
        if (e.y) atomicAdd(&acc[w][e.y >> 16], __uint_as_float((e.y & 0xFFFFu) << 16));
        if (e.z) atomicAdd(&acc[w][e.z >> 16], __uint_as_float((e.z & 0xFFFFu) << 16));
        if (e.w) atomicAdd(&acc[w][e.w >> 16], __uint_as_float((e.w & 0xFFFFu) << 16));
    }
    __syncthreads();
    size_t ob = (size_t)b * RANGE;
    for (int i = tid; i < RANGE; i += TB) {
        float v = acc[0][i] + acc[1][i] + acc[2][i] + acc[3][i];
        if (add_prev) v += out[ob + i];
        out[ob + i] = v;
    }
}

// ---- Fallback path: zero + device atomics ----
__global__ __launch_bounds__(TB) void zero_kernel(f32x4* __restrict__ p, int n4) {
    int i = blockIdx.x * blockDim.x + threadIdx.x;
    if (i < n4) p[i] = (f32x4)(0.f);
}

__global__ __launch_bounds__(TB) void atomic_fallback_kernel(
        const i32x4* __restrict__ bt, const i32x4* __restrict__ ai,
        const f32x4* __restrict__ bs_, const f32x4* __restrict__ bp_,
        const f32x4* __restrict__ bpp_, const float* __restrict__ bond_params,
        float* __restrict__ out, int n4) {
    __shared__ float sp[80];
    if (threadIdx.x < 80) sp[threadIdx.x] = bond_params[threadIdx.x];
    __syncthreads();
    int i = blockIdx.x * blockDim.x + threadIdx.x;
    if (i >= n4) return;
    i32x4 t  = bt[i]; i32x4 a = ai[i];
    f32x4 s  = bs_[i]; f32x4 p = bp_[i]; f32x4 pp = bpp_[i];
#pragma unroll
    for (int k = 0; k < 4; ++k) {
        const float* pr = sp + t[k] * 5;
        float pw = __powf(s[k], pr[4]);
        float e  = -pr[0] * s[k] * __expf(pr[3] * (1.0f - pw))
                   - pr[1] * p[k] - pr[2] * pp[k];
        unsafeAtomicAdd(&out[a[k]], e);
    }
}

extern "C" void kernel_launch(void* const* d_in, const int* in_sizes, int n_in,
                              void* d_out, int out_size, void* d_ws, size_t ws_size,
                              hipStream_t stream) {
    const int*   bond_type   = (const int*)  d_in[0];
    const int*   atom_i      = (const int*)  d_in[1];
    const float* bo_sigma    = (const float*)d_in[2];
    const float* bo_pi       = (const float*)d_in[3];
    const float* bo_pipi     = (const float*)d_in[4];
    const float* bond_params = (const float*)d_in[5];
    float*       e_atom      = (float*)d_out;

    const int n_bonds = in_sizes[0];
    const int n_atoms = out_size;

    // Preference: fewest rounds first; within a round count, CB=4096 (7 blocks/CU)
    // before CB=8192 (4 blocks/CU). First candidate whose worst-case padded
    // workspace fits wins.
    int cfg_cb = 0, cfg_nr = 0;
    if (n_atoms == (NB << SHIFT)) {
        const int prefs[10][2] = {
            {4096, 1}, {4096, 2}, {8192, 1}, {8192, 2}, {4096, 4},
            {8192, 4}, {4096, 8}, {8192, 8}, {4096, 16}, {8192, 16}};
        for (int ci = 0; ci < 10 && !cfg_nr; ++ci) {
            int cb = prefs[ci][0], r = prefs[ci][1];
            if (n_bonds % (r * cb)) continue;
            long cpr = (long)n_bonds / r, nsb = cpr / cb;
            if (nsb % 256 || nsb < 256 || nsb > 4096) continue;
            size_t arena_worst = (size_t)cpr + (size_t)(PADQ - 1) * NB * nsb;
            size_t need = arena_worst * 4
                        + (size_t)nsb * NB * 4      // offs (u32)
                        + (size_t)NB * 4            // total
                        + (size_t)NB * 4            // gbase
                        + (size_t)nsb * NB * 2      // counts (u16)
                        + 256;
            if (need <= ws_size) { cfg_cb = cb; cfg_nr = r; }
        }
    }

    if (cfg_nr) {
        const int NR = cfg_nr, cpr = n_bonds / NR, nsb = cpr / cfg_cb;
        size_t arena_worst = (size_t)cpr + (size_t)(PADQ - 1) * NB * nsb;
        u32* arena  = (u32*)d_ws;
        u32* offs   = arena + arena_worst;
        u32* total  = offs + (size_t)nsb * NB;
        u32* gbase  = total + NB;
        u16* counts = (u16*)(gbase + NB);
        for (int r = 0; r < NR; ++r) {
            int rs = r * cpr;
            if (cfg_cb == 4096)
                count_kernel<4096><<<nsb, TB, 0, stream>>>(
                    (const i32x4*)atom_i, counts, rs);
            else
                count_kernel<8192><<<nsb, TB, 0, stream>>>(
                    (const i32x4*)atom_i, counts, rs);
            scan_cols_kernel<<<NB, TB, 0, stream>>>(counts, offs, total, nsb);
            base_kernel<<<1, TB, 0, stream>>>(total, gbase);
            if (cfg_cb == 4096)
                partition_kernel<4096, 7><<<nsb, TB, 0, stream>>>(
                    (const i32x4*)bond_type, (const i32x4*)atom_i,
                    (const f32x4*)bo_sigma, (const f32x4*)bo_pi,
                    (const f32x4*)bo_pipi, bond_params,
                    counts, offs, gbase, arena, rs);
            else
                partition_kernel<8192, 4><<<nsb, TB, 0, stream>>>(
                    (const i32x4*)bond_type, (const i32x4*)atom_i,
                    (const f32x4*)bo_sigma, (const f32x4*)bo_pi,
                    (const f32x4*)bo_pipi, bond_params,
                    counts, offs, gbase, arena, rs);
            accum_kernel<<<NB, TB, 0, stream>>>(arena, total, gbase, e_atom,
                                                r ? 1 : 0);
        }
    } else {
        int zn4 = n_atoms / 4;
        zero_kernel<<<(zn4 + TB - 1) / TB, TB, 0, stream>>>((f32x4*)e_atom, zn4);
        int n4 = n_bonds / 4;
        atomic_fallback_kernel<<<(n4 + TB - 1) / TB, TB, 0, stream>>>(
            (const i32x4*)bond_type, (const i32x4*)atom_i,
            (const f32x4*)bo_sigma, (const f32x4*)bo_pi, (const f32x4*)bo_pipi,
            bond_params, e_atom, n4);
    }
}

// Round 2
// 446.849 us; speedup vs baseline: 1.0239x; 1.0239x over previous
//
#include <hip/hip_runtime.h>

// ReaxFF bond energy + segment_sum. N_BONDS=16777216, N_ATOMS=1048576, N_TYPES=16.
//
// R5: LDS counting sort + sector-aligned run writes -> 181 us partition.
// R6: CB=8192, 3 blocks/CU (occ 36%) -> 125 us partition.
// R7: CB=4096, occ 64% -> 136 us. LESSON: wave count is NOT the limiter;
//     per-wave MLP is (VGPR=36 -> no load pipelining), and WRITE shows ~2x
//     amplification (32B runs from different XCDs share 64B granules ->
//     cross-L2 partial-line RMW).
// R8 (this): CB=8192 + PADQ=16 (runs own whole 64B granules; avg run len 16),
//     XCD-chunked sb swizzle (adjacent runs -> same L2), explicit register
//     prefetch of next iteration's 5 payload vectors (double the in-flight
//     loads per wave), drop nontemporal (use the L2 streaming path),
//     gofs precomputed in LDS for copy-out, accum TB=1024 (32 waves/CU).

typedef float f32x4 __attribute__((ext_vector_type(4)));
typedef int   i32x4 __attribute__((ext_vector_type(4)));
typedef unsigned u32;
typedef unsigned short u16;

#define NB     512      // buckets; bucket covers 2048 atoms
#define RANGE  2048
#define SHIFT  11
#define TB     256
#define PADQ   16u      // run padding quantum (16 elems = 64 B granule)

__device__ __forceinline__ u32 f32_to_bf16_bits(float f) {
    u32 u = __float_as_uint(f);
    return ((u + 0x7FFFu + ((u >> 16) & 1u)) >> 16) & 0xFFFFu;
}

// exclusive prefix over the 256-thread block of per-thread value v.
__device__ __forceinline__ u32 block_excl_scan(u32 v, u32* wsum, int tid) {
    u32 s = v;
#pragma unroll
    for (int off = 1; off < 64; off <<= 1) {
        u32 n = __shfl_up(s, off);
        if ((tid & 63) >= off) s += n;
    }
    if ((tid & 63) == 63) wsum[tid >> 6] = s;
    __syncthreads();
    int w = tid >> 6;
    u32 wb = 0;
#pragma unroll
    for (int ww = 0; ww < 3; ++ww) wb += (ww < w) ? wsum[ww] : 0u;
    return wb + s - v;
}

// ---- Pass A: per-superblock bucket counts (per-wave LDS hist) ----
template<int CBK>
__global__ __launch_bounds__(TB) void count_kernel(
        const i32x4* __restrict__ atom_i, u16* __restrict__ counts,
        int round_start) {
    __shared__ u32 hist[4][NB];
    int tid = threadIdx.x, w = tid >> 6;
    for (int i = tid; i < 4 * NB; i += TB) ((u32*)hist)[i] = 0u;
    __syncthreads();
    long base4 = ((long)round_start + (long)blockIdx.x * CBK) >> 2;
#pragma unroll
    for (int it = 0; it < CBK / (TB * 4); ++it) {
        i32x4 a = atom_i[base4 + it * TB + tid];
        atomicAdd(&hist[w][(u32)a.x >> SHIFT], 1u);
        atomicAdd(&hist[w][(u32)a.y >> SHIFT], 1u);
        atomicAdd(&hist[w][(u32)a.z >> SHIFT], 1u);
        atomicAdd(&hist[w][(u32)a.w >> SHIFT], 1u);
    }
    __syncthreads();
    for (int b = tid; b < NB; b += TB)
        counts[(size_t)blockIdx.x * NB + b] =
            (u16)(hist[0][b] + hist[1][b] + hist[2][b] + hist[3][b]);
}

// ---- S1: per-bucket exclusive scan of PADDED counts over superblocks ----
__global__ __launch_bounds__(TB) void scan_cols_kernel(
        const u16* __restrict__ counts, u32* __restrict__ offs,
        u32* __restrict__ total, int nsb) {
    __shared__ u32 sc[TB];
    int b = blockIdx.x, t = threadIdx.x;
    int vpt = nsb >> 8;                 // nsb multiple of 256, vpt <= 16
    u32 v[16];
    u32 s = 0;
    for (int k = 0; k < vpt; ++k) {
        u32 c = counts[(size_t)(t * vpt + k) * NB + b];
        c = (c + PADQ - 1u) & ~(PADQ - 1u);
        v[k] = s; s += c;
    }
    sc[t] = s;
    __syncthreads();
    for (int off = 1; off < TB; off <<= 1) {
        u32 u = (t >= off) ? sc[t - off] : 0u;
        __syncthreads();
        sc[t] += u;
        __syncthreads();
    }
    u32 excl = sc[t] - s;
    for (int k = 0; k < vpt; ++k)
        offs[(size_t)(t * vpt + k) * NB + b] = excl + v[k];
    if (t == TB - 1) total[b] = sc[t];
}

// ---- S2: bucket base = exclusive prefix of padded bucket totals (once) ----
__global__ __launch_bounds__(TB) void base_kernel(
        const u32* __restrict__ total, u32* __restrict__ gbase) {
    __shared__ u32 wsum[4];
    int t = threadIdx.x;
    u32 t0 = total[2 * t], t1 = total[2 * t + 1];
    u32 excl = block_excl_scan(t0 + t1, wsum, t);
    gbase[2 * t]     = excl;
    gbase[2 * t + 1] = excl + t0;
}

// ---- Pass B: compute e, LDS counting sort, coalesced padded run writes ----
template<int CBK, int MINB>
__global__ __launch_bounds__(TB, MINB) void partition_kernel(
        const i32x4* __restrict__ bt, const i32x4* __restrict__ ai,
        const f32x4* __restrict__ bs_, const f32x4* __restrict__ bp_,
        const f32x4* __restrict__ bpp_, const float* __restrict__ bond_params,
        const u16* __restrict__ counts, const u32* __restrict__ offs,
        const u32* __restrict__ gbase, u32* __restrict__ arena,
        int round_start) {
    __shared__ u32   sorted[CBK];       // 32 KB (8192)
    __shared__ u32   start_[NB], cur[NB], gofs[NB];
    __shared__ u32   wsum[4];
    __shared__ float4 sp_a[16];         // de_s, de_p, de_pp, p_be1
    __shared__ float  sp_b[16];         // p_be2

    int tid = threadIdx.x;
    // XCD-chunked swizzle: consecutive sb (whose runs are adjacent in the
    // arena) land on the same XCD/L2 so partial-line writes merge.
    int nsbK = gridDim.x, bid = blockIdx.x;
    int sb = ((nsbK & 7) == 0) ? ((bid & 7) * (nsbK >> 3) + (bid >> 3)) : bid;

    if (tid < 16) {
        const float* p = bond_params + tid * 5;
        sp_a[tid] = make_float4(p[0], p[1], p[2], p[3]);
        sp_b[tid] = p[4];
    }
    // gofs[b] = global base for this superblock's run in bucket b
    for (int b = tid; b < NB; b += TB)
        gofs[b] = gbase[b] + offs[(size_t)sb * NB + b];
    // count row -> cursor starts (local layout)
    u32 c01 = ((const u32*)(counts + (size_t)sb * NB))[tid];
    u32 c0 = c01 & 0xFFFFu, c1 = c01 >> 16;
    u32 excl = block_excl_scan(c0 + c1, wsum, tid);
    start_[2 * tid]     = excl;       cur[2 * tid]     = excl;
    start_[2 * tid + 1] = excl + c0;  cur[2 * tid + 1] = excl + c0;
    __syncthreads();

    constexpr int ITERS = CBK / (TB * 4);
    long base4 = ((long)round_start + (long)sb * CBK) >> 2;
    // software pipeline: prefetch next iteration's 5 payload vectors while
    // processing the current one (keeps ~10 dwordx4 loads in flight / wave).
    i32x4 tA = bt[base4 + tid], aA = ai[base4 + tid];
    f32x4 sA = bs_[base4 + tid], pA = bp_[base4 + tid], ppA = bpp_[base4 + tid];
#pragma unroll
    for (int it = 0; it < ITERS; ++it) {
        i32x4 tN, aN; f32x4 sN, pN, ppN;
        if (it + 1 < ITERS) {
            long nidx = base4 + (it + 1) * TB + tid;
            tN = bt[nidx]; aN = ai[nidx];
            sN = bs_[nidx]; pN = bp_[nidx]; ppN = bpp_[nidx];
        }
#pragma unroll
        for (int k = 0; k < 4; ++k) {
            u32 ak = (u32)aA[k];
            float4 pa = sp_a[tA[k]];     // one ds_read_b128
            float  pb = sp_b[tA[k]];     // one ds_read_b32
            float pw = __powf(sA[k], pb); // s in (0.05,1) -> safe
            float e  = -pa.x * sA[k] * __expf(pa.w * (1.0f - pw))
                       - pa.y * pA[k] - pa.z * ppA[k];
            u32 b = ak >> SHIFT;
            u32 pos = atomicAdd(&cur[b], 1u);
            sorted[pos] = ((ak & (RANGE - 1u)) << 16) | f32_to_bf16_bits(e);
        }
        tA = tN; aA = aN; sA = sN; pA = pN; ppA = ppN;
    }
    __syncthreads();

    // copy-out: 16 lanes per bucket, runs 64B-aligned (PADQ=16)
    constexpr int LG  = 16;
    constexpr int GPW = 64 / LG;        // 4 bucket groups per wave
    int w = tid >> 6, lane = tid & 63;
    int gi = lane / LG, j0 = lane % LG;
    for (int b = w * GPW + gi; b < NB; b += 4 * GPW) {
        u32 end = cur[b], ls = start_[b], len = end - ls;
        u32 plen = (len + PADQ - 1u) & ~(PADQ - 1u);
        u32 g = gofs[b];
        for (u32 j = j0; j < plen; j += LG)
            arena[g + j] = (j < len) ? sorted[ls + j] : 0u;
    }
}

// ---- Pass C: per-bucket LDS accumulation (per-wave replicas) ----
// TB=1024: grid is only NB=512 blocks (2/CU) -> need fat blocks for MLP.
__global__ __launch_bounds__(1024) void accum_kernel(
        const u32* __restrict__ arena, const u32* __restrict__ total,
        const u32* __restrict__ gbase, float* __restrict__ out, int add_prev) {
    __shared__ float acc[4][RANGE];     // 32 KB, 4 replicas shared by 16 waves
    int tid = threadIdx.x, w = (tid >> 6) & 3, b = blockIdx.x;
    for (int i = tid; i < 4 * RANGE; i += 1024) ((float*)acc)[i] = 0.f;
    __syncthreads();
    u32 s0 = gbase[b];                  // exclusive prefix of padded totals
    u32 n  = total[b];                  // multiple of 16
    const uint4* src = (const uint4*)(arena + s0);
    for (u32 j = tid; j < (n >> 2); j += 1024) {
        uint4 e = src[j];
        if (e.x) atomicAdd(&acc[w][e.x >> 16], __uint_as_float((e.x & 0xFFFFu) << 16));
        if (e.y) atomicAdd(&acc[w][e.y >> 16], __uint_as_float((e.y & 0xFFFFu) << 16));
        if (e.z) atomicAdd(&acc[w][e.z >> 16], __uint_as_float((e.z & 0xFFFFu) << 16));
        if (e.w) atomicAdd(&acc[w][e.w >> 16], __uint_as_float((e.w & 0xFFFFu) << 16));
    }
    __syncthreads();
    size_t ob = (size_t)b * RANGE;
    for (int i = tid; i < RANGE; i += 1024) {
        float v = acc[0][i] + acc[1][i] + acc[2][i] + acc[3][i];
        if (add_prev) v += out[ob + i];
        out[ob + i] = v;
    }
}

// ---- Fallback path: zero + device atomics ----
__global__ __launch_bounds__(TB) void zero_kernel(f32x4* __restrict__ p, int n4) {
    int i = blockIdx.x * blockDim.x + threadIdx.x;
    if (i < n4) p[i] = (f32x4)(0.f);
}

__global__ __launch_bounds__(TB) void atomic_fallback_kernel(
        const i32x4* __restrict__ bt, const i32x4* __restrict__ ai,
        const f32x4* __restrict__ bs_, const f32x4* __restrict__ bp_,
        const f32x4* __restrict__ bpp_, const float* __restrict__ bond_params,
        float* __restrict__ out, int n4) {
    __shared__ float sp[80];
    if (threadIdx.x < 80) sp[threadIdx.x] = bond_params[threadIdx.x];
    __syncthreads();
    int i = blockIdx.x * blockDim.x + threadIdx.x;
    if (i >= n4) return;
    i32x4 t  = bt[i]; i32x4 a = ai[i];
    f32x4 s  = bs_[i]; f32x4 p = bp_[i]; f32x4 pp = bpp_[i];
#pragma unroll
    for (int k = 0; k < 4; ++k) {
        const float* pr = sp + t[k] * 5;
        float pw = __powf(s[k], pr[4]);
        float e  = -pr[0] * s[k] * __expf(pr[3] * (1.0f - pw))
                   - pr[1] * p[k] - pr[2] * pp[k];
        unsafeAtomicAdd(&out[a[k]], e);
    }
}

extern "C" void kernel_launch(void* const* d_in, const int* in_sizes, int n_in,
                              void* d_out, int out_size, void* d_ws, size_t ws_size,
                              hipStream_t stream) {
    const int*   bond_type   = (const int*)  d_in[0];
    const int*   atom_i      = (const int*)  d_in[1];
    const float* bo_sigma    = (const float*)d_in[2];
    const float* bo_pi       = (const float*)d_in[3];
    const float* bo_pipi     = (const float*)d_in[4];
    const float* bond_params = (const float*)d_in[5];
    float*       e_atom      = (float*)d_out;

    const int n_bonds = in_sizes[0];
    const int n_atoms = out_size;

    // Preference: fewest rounds first; CB=8192 preferred (longer runs ->
    // less PADQ waste; occupancy >=36% shown not to matter).
    int cfg_cb = 0, cfg_nr = 0;
    if (n_atoms == (NB << SHIFT)) {
        const int prefs[10][2] = {
            {8192, 1}, {4096, 1}, {8192, 2}, {4096, 2}, {8192, 4},
            {4096, 4}, {8192, 8}, {4096, 8}, {8192, 16}, {4096, 16}};
        for (int ci = 0; ci < 10 && !cfg_nr; ++ci) {
            int cb = prefs[ci][0], r = prefs[ci][1];
            if (n_bonds % (r * cb)) continue;
            long cpr = (long)n_bonds / r, nsb = cpr / cb;
            if (nsb % 256 || nsb < 256 || nsb > 4096) continue;
            size_t arena_worst = (size_t)cpr + (size_t)(PADQ - 1) * NB * nsb;
            size_t need = arena_worst * 4
                        + (size_t)nsb * NB * 4      // offs (u32)
                        + (size_t)NB * 4            // total
                        + (size_t)NB * 4            // gbase
                        + (size_t)nsb * NB * 2      // counts (u16)
                        + 256;
            if (need <= ws_size) { cfg_cb = cb; cfg_nr = r; }
        }
    }

    if (cfg_nr) {
        const int NR = cfg_nr, cpr = n_bonds / NR, nsb = cpr / cfg_cb;
        size_t arena_worst = (size_t)cpr + (size_t)(PADQ - 1) * NB * nsb;
        u32* arena  = (u32*)d_ws;
        u32* offs   = arena + arena_worst;
        u32* total  = offs + (size_t)nsb * NB;
        u32* gbase  = total + NB;
        u16* counts = (u16*)(gbase + NB);
        for (int r = 0; r < NR; ++r) {
            int rs = r * cpr;
            if (cfg_cb == 4096)
                count_kernel<4096><<<nsb, TB, 0, stream>>>(
                    (const i32x4*)atom_i, counts, rs);
            else
                count_kernel<8192><<<nsb, TB, 0, stream>>>(
                    (const i32x4*)atom_i, counts, rs);
            scan_cols_kernel<<<NB, TB, 0, stream>>>(counts, offs, total, nsb);
            base_kernel<<<1, TB, 0, stream>>>(total, gbase);
            if (cfg_cb == 4096)
                partition_kernel<4096, 4><<<nsb, TB, 0, stream>>>(
                    (const i32x4*)bond_type, (const i32x4*)atom_i,
                    (const f32x4*)bo_sigma, (const f32x4*)bo_pi,
                    (const f32x4*)bo_pipi, bond_params,
                    counts, offs, gbase, arena, rs);
            else
                partition_kernel<8192, 4><<<nsb, TB, 0, stream>>>(
                    (const i32x4*)bond_type, (const i32x4*)atom_i,
                    (const f32x4*)bo_sigma, (const f32x4*)bo_pi,
                    (const f32x4*)bo_pipi, bond_params,
                    counts, offs, gbase, arena, rs);
            accum_kernel<<<NB, 1024, 0, stream>>>(arena, total, gbase, e_atom,
                                                  r ? 1 : 0);
        }
    } else {
        int zn4 = n_atoms / 4;
        zero_kernel<<<(zn4 + TB - 1) / TB, TB, 0, stream>>>((f32x4*)e_atom, zn4);
        int n4 = n_bonds / 4;
        atomic_fallback_kernel<<<(n4 + TB - 1) / TB, TB, 0, stream>>>(
            (const i32x4*)bond_type, (const i32x4*)atom_i,
            (const f32x4*)bo_sigma, (const f32x4*)bo_pi, (const f32x4*)bo_pipi,
            bond_params, e_atom, n4);
    }
}

// Round 4
// 423.605 us; speedup vs baseline: 1.0801x; 1.0549x over previous
//
#include <hip/hip_runtime.h>

// ReaxFF bond energy + segment_sum. N_BONDS=16777216, N_ATOMS=1048576, N_TYPES=16.
//
// R5: LDS counting sort + sector-aligned run writes -> 181 us partition.
// R6: CB=8192, 512 buckets, NR=2 -> 125 us/round partition (best per-bond rate).
// R7: CB=4096, occ 64% -> 136 us. Occupancy is NOT the limiter.
// R8: PADQ=16 + XCD swizzle + prefetch -> 144 us. Write-"amplification" (~1.9x)
//     is invariant to alignment/swizzle -> counter artifact or intrinsic;
//     prefetch was already done by compiler (VGPR 52 unchanged).
// R9: structural overhead cut. 64 coarse buckets (16K atoms each):
//     runs avg 128 elems -> full-wave coalesced copy-out, pad waste 50%->6%,
//     wave-shfl prologue scan, NR=1 (fits ws ~92 MB). Accum: 64 KB LDS f32
//     acc per block, 4 splits x 64 buckets, unconditional LDS atomics,
//     partials + merge kernel (no replica-sum pass). Partition loop = R6 form.
// R10 (this): fix compile — __builtin_nontemporal_load needs a clang
//     ext_vector pointer, not HIP's uint4 class. Added u32x4 typedef.

typedef float    f32x4 __attribute__((ext_vector_type(4)));
typedef int      i32x4 __attribute__((ext_vector_type(4)));
typedef unsigned u32x4 __attribute__((ext_vector_type(4)));
typedef unsigned u32;
typedef unsigned short u16;

#define NBUK   64       // coarse buckets; bucket covers 16384 atoms
#define RANGEK 16384
#define SHIFTK 14
#define CB     8192     // bonds per superblock
#define TB     256
#define PADQ   16u      // run padding quantum (16 elems = 64 B granule)
#define SPLITS 4        // accum blocks per bucket

__device__ __forceinline__ u32 f32_to_bf16_bits(float f) {
    u32 u = __float_as_uint(f);
    return ((u + 0x7FFFu + ((u >> 16) & 1u)) >> 16) & 0xFFFFu;
}

// ---- Pass A: per-superblock bucket counts (per-wave LDS hist) ----
__global__ __launch_bounds__(TB) void count_kernel(
        const i32x4* __restrict__ atom_i, u16* __restrict__ counts,
        int round_start) {
    __shared__ u32 hist[4][NBUK];
    int tid = threadIdx.x, w = tid >> 6;
    if (tid < 4 * NBUK) ((u32*)hist)[tid] = 0u;
    __syncthreads();
    long base4 = ((long)round_start + (long)blockIdx.x * CB) >> 2;
#pragma unroll
    for (int it = 0; it < CB / (TB * 4); ++it) {
        i32x4 a = __builtin_nontemporal_load(&atom_i[base4 + it * TB + tid]);
        atomicAdd(&hist[w][(u32)a.x >> SHIFTK], 1u);
        atomicAdd(&hist[w][(u32)a.y >> SHIFTK], 1u);
        atomicAdd(&hist[w][(u32)a.z >> SHIFTK], 1u);
        atomicAdd(&hist[w][(u32)a.w >> SHIFTK], 1u);
    }
    __syncthreads();
    if (tid < NBUK)
        counts[(size_t)blockIdx.x * NBUK + tid] =
            (u16)(hist[0][tid] + hist[1][tid] + hist[2][tid] + hist[3][tid]);
}

// ---- S1: per-bucket exclusive scan of PADDED counts over superblocks ----
// grid = NBUK blocks; block b scans column b over nsb superblocks.
__global__ __launch_bounds__(TB) void scan_cols_kernel(
        const u16* __restrict__ counts, u32* __restrict__ offs,
        u32* __restrict__ total, int nsb) {
    __shared__ u32 sc[TB];
    int b = blockIdx.x, t = threadIdx.x;
    int vpt = nsb >> 8;                 // nsb multiple of 256, vpt <= 8
    u32 v[8];
    u32 s = 0;
    for (int k = 0; k < vpt; ++k) {
        u32 c = counts[(size_t)(t * vpt + k) * NBUK + b];
        c = (c + PADQ - 1u) & ~(PADQ - 1u);
        v[k] = s; s += c;
    }
    sc[t] = s;
    __syncthreads();
    for (int off = 1; off < TB; off <<= 1) {
        u32 u = (t >= off) ? sc[t - off] : 0u;
        __syncthreads();
        sc[t] += u;
        __syncthreads();
    }
    u32 excl = sc[t] - s;
    for (int k = 0; k < vpt; ++k)
        offs[(size_t)(t * vpt + k) * NBUK + b] = excl + v[k];
    if (t == TB - 1) total[b] = sc[t];
}

// ---- S2: bucket base = exclusive prefix of padded bucket totals ----
// 1 block x 64 threads (one wave).
__global__ __launch_bounds__(64) void base_kernel(
        const u32* __restrict__ total, u32* __restrict__ gbase) {
    int t = threadIdx.x;
    u32 v = total[t];
    u32 s = v;
#pragma unroll
    for (int off = 1; off < 64; off <<= 1) {
        u32 n = __shfl_up(s, off);
        if (t >= off) s += n;
    }
    gbase[t] = s - v;
}

// ---- Pass B: compute e, LDS counting sort (64 buckets), run writes ----
__global__ __launch_bounds__(TB, 4) void partition_kernel(
        const i32x4* __restrict__ bt, const i32x4* __restrict__ ai,
        const f32x4* __restrict__ bs_, const f32x4* __restrict__ bp_,
        const f32x4* __restrict__ bpp_, const float* __restrict__ bond_params,
        const u16* __restrict__ counts, const u32* __restrict__ offs,
        const u32* __restrict__ gbase, u32* __restrict__ arena,
        int round_start) {
    __shared__ u32   sorted[CB];        // 32 KB
    __shared__ u32   start_[NBUK], cur[NBUK], gofs[NBUK];
    __shared__ float4 sp_a[16];         // de_s, de_p, de_pp, p_be1
    __shared__ float  sp_b[16];         // p_be2

    int tid = threadIdx.x, sb = blockIdx.x;
    if (tid < 16) {
        const float* p = bond_params + tid * 5;
        sp_a[tid] = make_float4(p[0], p[1], p[2], p[3]);
        sp_b[tid] = p[4];
    }
    // prologue: wave 0 scans the 64 counts with shfl; no block scan needed
    if (tid < 64) {
        u32 c = counts[(size_t)sb * NBUK + tid];
        u32 s = c;
#pragma unroll
        for (int off = 1; off < 64; off <<= 1) {
            u32 n = __shfl_up(s, off);
            if (tid >= off) s += n;
        }
        u32 excl = s - c;
        start_[tid] = excl;
        cur[tid]    = excl;
        gofs[tid]   = gbase[tid] + offs[(size_t)sb * NBUK + tid];
    }
    __syncthreads();

    long base4 = ((long)round_start + (long)sb * CB) >> 2;
#pragma unroll
    for (int it = 0; it < CB / (TB * 4); ++it) {
        long idx = base4 + it * TB + tid;
        i32x4 t  = __builtin_nontemporal_load(&bt[idx]);
        i32x4 a  = __builtin_nontemporal_load(&ai[idx]);
        f32x4 s  = __builtin_nontemporal_load(&bs_[idx]);
        f32x4 p  = __builtin_nontemporal_load(&bp_[idx]);
        f32x4 pp = __builtin_nontemporal_load(&bpp_[idx]);
#pragma unroll
        for (int k = 0; k < 4; ++k) {
            u32 ak = (u32)a[k];
            float4 pa = sp_a[t[k]];      // one ds_read_b128
            float  pb = sp_b[t[k]];      // one ds_read_b32
            float pw = __powf(s[k], pb); // s in (0.05,1) -> safe
            float e  = -pa.x * s[k] * __expf(pa.w * (1.0f - pw))
                       - pa.y * p[k] - pa.z * pp[k];
            u32 b = ak >> SHIFTK;
            u32 pos = atomicAdd(&cur[b], 1u);
            sorted[pos] = ((ak & (RANGEK - 1u)) << 16) | f32_to_bf16_bits(e);
        }
    }
    __syncthreads();

    // copy-out: one wave per bucket (runs avg 128 elems), 64-lane stride
    int w = tid >> 6, lane = tid & 63;
    for (int b = w; b < NBUK; b += 4) {
        u32 end = cur[b], ls = start_[b], len = end - ls;
        u32 plen = (len + PADQ - 1u) & ~(PADQ - 1u);
        u32 g = gofs[b];
        for (u32 j = lane; j < plen; j += 64u)
            arena[g + j] = (j < len) ? sorted[ls + j] : 0u;
    }
}

// ---- Pass C: per-bucket-split LDS f32 accumulation (64 KB acc) ----
__global__ __launch_bounds__(1024) void accum_kernel(
        const u32* __restrict__ arena, const u32* __restrict__ total,
        const u32* __restrict__ gbase, float* __restrict__ partials) {
    __shared__ float acc[RANGEK];       // 64 KB
    int tid = threadIdx.x;
    int b = blockIdx.x >> 2, sp = blockIdx.x & 3;
    f32x4* a4 = (f32x4*)acc;
#pragma unroll
    for (int i = 0; i < RANGEK / 4 / 1024; ++i)
        a4[i * 1024 + tid] = (f32x4)(0.f);
    __syncthreads();
    u32 s0 = gbase[b];
    u32 n  = total[b];                  // multiple of 16
    u32 qs = n >> 4;                    // u32x4s per split (n/16, exact)
    const u32x4* src = (const u32x4*)(arena + s0) + (size_t)sp * qs;
    for (u32 j = tid; j < qs; j += 1024) {
        u32x4 e = __builtin_nontemporal_load(&src[j]);
        // pad entries are 0 -> add 0.0f to acc[0]: harmless, branch-free
        atomicAdd(&acc[e.x >> 16], __uint_as_float((e.x & 0xFFFFu) << 16));
        atomicAdd(&acc[e.y >> 16], __uint_as_float((e.y & 0xFFFFu) << 16));
        atomicAdd(&acc[e.z >> 16], __uint_as_float((e.z & 0xFFFFu) << 16));
        atomicAdd(&acc[e.w >> 16], __uint_as_float((e.w & 0xFFFFu) << 16));
    }
    __syncthreads();
    f32x4* pr = (f32x4*)(partials + ((size_t)sp * NBUK + b) * RANGEK);
#pragma unroll
    for (int i = 0; i < RANGEK / 4 / 1024; ++i)
        pr[i * 1024 + tid] = a4[i * 1024 + tid];
}

// ---- Merge: out = (add_prev ? out : 0) + sum of SPLITS partials ----
__global__ __launch_bounds__(TB) void merge_kernel(
        const float* __restrict__ partials, float* __restrict__ out,
        int n_atoms, int add_prev) {
    int i = blockIdx.x * TB + threadIdx.x;
    const f32x4* p0 = (const f32x4*)partials;
    const f32x4* p1 = (const f32x4*)(partials + (size_t)n_atoms);
    const f32x4* p2 = (const f32x4*)(partials + 2 * (size_t)n_atoms);
    const f32x4* p3 = (const f32x4*)(partials + 3 * (size_t)n_atoms);
    f32x4* o4 = (f32x4*)out;
    f32x4 v = p0[i] + p1[i] + p2[i] + p3[i];
    if (add_prev) v += o4[i];
    o4[i] = v;
}

// ---- Fallback path: zero + device atomics ----
__global__ __launch_bounds__(TB) void zero_kernel(f32x4* __restrict__ p, int n4) {
    int i = blockIdx.x * blockDim.x + threadIdx.x;
    if (i < n4) p[i] = (f32x4)(0.f);
}

__global__ __launch_bounds__(TB) void atomic_fallback_kernel(
        const i32x4* __restrict__ bt, const i32x4* __restrict__ ai,
        const f32x4* __restrict__ bs_, const f32x4* __restrict__ bp_,
        const f32x4* __restrict__ bpp_, const float* __restrict__ bond_params,
        float* __restrict__ out, int n4) {
    __shared__ float sp[80];
    if (threadIdx.x < 80) sp[threadIdx.x] = bond_params[threadIdx.x];
    __syncthreads();
    int i = blockIdx.x * blockDim.x + threadIdx.x;
    if (i >= n4) return;
    i32x4 t  = bt[i]; i32x4 a = ai[i];
    f32x4 s  = bs_[i]; f32x4 p = bp_[i]; f32x4 pp = bpp_[i];
#pragma unroll
    for (int k = 0; k < 4; ++k) {
        const float* pr = sp + t[k] * 5;
        float pw = __powf(s[k], pr[4]);
        float e  = -pr[0] * s[k] * __expf(pr[3] * (1.0f - pw))
                   - pr[1] * p[k] - pr[2] * pp[k];
        unsafeAtomicAdd(&out[a[k]], e);
    }
}

extern "C" void kernel_launch(void* const* d_in, const int* in_sizes, int n_in,
                              void* d_out, int out_size, void* d_ws, size_t ws_size,
                              hipStream_t stream) {
    const int*   bond_type   = (const int*)  d_in[0];
    const int*   atom_i      = (const int*)  d_in[1];
    const float* bo_sigma    = (const float*)d_in[2];
    const float* bo_pi       = (const float*)d_in[3];
    const float* bo_pipi     = (const float*)d_in[4];
    const float* bond_params = (const float*)d_in[5];
    float*       e_atom      = (float*)d_out;

    const int n_bonds = in_sizes[0];
    const int n_atoms = out_size;

    // Fewest rounds whose worst-case padded workspace fits.
    int cfg_nr = 0;
    if (n_atoms == (NBUK << SHIFTK)) {
        const int cands[5] = {1, 2, 4, 8, 16};
        for (int ci = 0; ci < 5 && !cfg_nr; ++ci) {
            int r = cands[ci];
            if (n_bonds % (r * CB)) continue;
            long cpr = (long)n_bonds / r, nsb = cpr / CB;
            if (nsb % 256 || nsb < 256 || nsb > 4096) continue;
            size_t arena_worst = (size_t)cpr + (size_t)(PADQ - 1) * NBUK * nsb;
            size_t need = arena_worst * 4
                        + (size_t)nsb * NBUK * 4        // offs (u32)
                        + (size_t)NBUK * 8              // total + gbase
                        + (size_t)nsb * NBUK * 2        // counts (u16)
                        + (size_t)SPLITS * n_atoms * 4  // partials (f32)
                        + 256;
            if (need <= ws_size) cfg_nr = r;
        }
    }

    if (cfg_nr) {
        const int NR = cfg_nr, cpr = n_bonds / NR, nsb = cpr / CB;
        size_t arena_worst = (size_t)cpr + (size_t)(PADQ - 1) * NBUK * nsb;
        u32*   arena    = (u32*)d_ws;
        u32*   offs     = arena + arena_worst;
        u32*   total    = offs + (size_t)nsb * NBUK;
        u32*   gbase    = total + NBUK;
        u16*   counts   = (u16*)(gbase + NBUK);
        float* partials = (float*)(counts + (size_t)nsb * NBUK);
        for (int r = 0; r < NR; ++r) {
            int rs = r * cpr;
            count_kernel<<<nsb, TB, 0, stream>>>((const i32x4*)atom_i, counts, rs);
            scan_cols_kernel<<<NBUK, TB, 0, stream>>>(counts, offs, total, nsb);
            base_kernel<<<1, 64, 0, stream>>>(total, gbase);
            partition_kernel<<<nsb, TB, 0, stream>>>(
                (const i32x4*)bond_type, (const i32x4*)atom_i,
                (const f32x4*)bo_sigma, (const f32x4*)bo_pi, (const f32x4*)bo_pipi,
                bond_params, counts, offs, gbase, arena, rs);
            accum_kernel<<<NBUK * SPLITS, 1024, 0, stream>>>(
                arena, total, gbase, partials);
            merge_kernel<<<n_atoms / 4 / TB, TB, 0, stream>>>(
                partials, e_atom, n_atoms, r ? 1 : 0);
        }
    } else {
        int zn4 = n_atoms / 4;
        zero_kernel<<<(zn4 + TB - 1) / TB, TB, 0, stream>>>((f32x4*)e_atom, zn4);
        int n4 = n_bonds / 4;
        atomic_fallback_kernel<<<(n4 + TB - 1) / TB, TB, 0, stream>>>(
            (const i32x4*)bond_type, (const i32x4*)atom_i,
            (const f32x4*)bo_sigma, (const f32x4*)bo_pi, (const f32x4*)bo_pipi,
            bond_params, e_atom, n4);
    }
}